// Round 1
// baseline (1133.336 us; speedup 1.0000x reference)
//
#include <hip/hip_runtime.h>
#include <hip/hip_bf16.h>
#include <math.h>

#define TSTEPS 128
#define HD 16      // GRU hidden
#define G3 48      // 3*H gates
#define AD 32      // 2*H attention dim

__device__ __forceinline__ float fast_sigmoid(float x) {
    return 1.0f / (1.0f + __expf(-x));
}
__device__ __forceinline__ float fast_tanh(float x) {
    // tanh(x) = 1 - 2/(exp(2x)+1); stable at both extremes
    return 1.0f - 2.0f / (__expf(2.0f * x) + 1.0f);
}

// One block = one sequence. 128 threads = 2 waves (wave0 fwd, wave1 bwd).
template<int D, bool HAS_PROJ>
__global__ __launch_bounds__(128, 1)
void gru_attn_kernel(
    const float* __restrict__ x,                      // [S, TSTEPS, D]
    const float* __restrict__ Wih_f, const float* __restrict__ Whh_f,
    const float* __restrict__ bih_f, const float* __restrict__ bhh_f,
    const float* __restrict__ Wih_b, const float* __restrict__ Whh_b,
    const float* __restrict__ bih_b, const float* __restrict__ bhh_b,
    const float* __restrict__ Wa, const float* __restrict__ ba,
    const float* __restrict__ ctxv,
    const float* __restrict__ Wm, const float* __restrict__ bm,
    float* __restrict__ out, int out_cols)
{
    __shared__ float x_sh[TSTEPS * D];
    __shared__ float gx_sh[2][TSTEPS][G3];
    __shared__ float h1_sh[TSTEPS][AD + 1];   // +1 pad: avoid stride-32 bank conflicts
    __shared__ float h_sh[2][HD];
    __shared__ float red[4];
    __shared__ float w_sh[TSTEPS];
    __shared__ float cv_sh[AD];

    const int tid  = threadIdx.x;
    const int seq  = blockIdx.x;
    const int lane = tid & 63;
    const int wave = tid >> 6;

    // ---- Phase 1: stage x into LDS (coalesced) ----
    const float* xp = x + (size_t)seq * TSTEPS * D;
    for (int i = tid; i < TSTEPS * D; i += 128)
        x_sh[i] = xp[i];
    __syncthreads();

    // ---- Phase 2: gx[dir][t][j] = bih[j] + sum_d x[t][d]*Wih[j][d] ----
    {
        const int t = tid;               // 128 threads == 128 timesteps
        float xr[D];
        #pragma unroll
        for (int d = 0; d < D; ++d) xr[d] = x_sh[t * D + d];
        for (int dir = 0; dir < 2; ++dir) {
            const float* Wih = dir ? Wih_b : Wih_f;
            const float* bih = dir ? bih_b : bih_f;
            for (int j = 0; j < G3; ++j) {
                float acc = bih[j];                    // uniform -> s_load
                #pragma unroll
                for (int d = 0; d < D; ++d)
                    acc += Wih[j * D + d] * xr[d];     // uniform weight -> s_load + v_fmac
                gx_sh[dir][t][j] = acc;
            }
        }
    }
    if (tid < 2 * HD) h_sh[tid >> 4][tid & 15] = 0.0f;
    __syncthreads();

    // ---- Phase 3: sequential recurrence. wave0 = fwd, wave1 = bwd ----
    {
        const int dir = wave;
        const float* Whh = dir ? Whh_b : Whh_f;
        const float* bhh = dir ? bhh_b : bhh_f;
        const int j = lane;              // gate index, valid for lane < 48
        float whh[HD];
        float bh = 0.0f;
        if (j < G3) {
            #pragma unroll
            for (int k = 0; k < HD; ++k) whh[k] = Whh[j * HD + k];
            bh = bhh[j];
        } else {
            #pragma unroll
            for (int k = 0; k < HD; ++k) whh[k] = 0.0f;
        }
        float h_own = 0.0f;              // lane k<16 keeps h[k]

        for (int s = 0; s < TSTEPS; ++s) {
            const int t = dir ? (TSTEPS - 1 - s) : s;
            // broadcast-read current h (uniform addresses -> conflict-free)
            float hv[HD];
            #pragma unroll
            for (int k = 0; k < HD; ++k) hv[k] = h_sh[dir][k];
            float gh = bh;
            #pragma unroll
            for (int k = 0; k < HD; ++k) gh += whh[k] * hv[k];
            const float gxv = gx_sh[dir][t][j < G3 ? j : 0];

            // lanes 0..31: r,z pre-activations; lanes 32..47: keep gxn/ghn separate
            const float sact = fast_sigmoid(gxv + gh);
            const float r    = __shfl(sact, lane - 32);       // n-lanes fetch r
            const float nv   = fast_tanh(gxv + r * gh);       // ghn includes bhh_n
            const float z    = __shfl(sact, lane + 16);       // h-lanes fetch z
            const float nn   = __shfl(nv,   lane + 32);       // h-lanes fetch n
            const float h_new = (1.0f - z) * nn + z * h_own;

            __syncthreads();             // everyone done reading old h
            if (lane < HD) {
                h_own = h_new;
                h_sh[dir][lane] = h_new;
                h1_sh[t][dir * HD + lane] = h_new;
            }
            __syncthreads();             // new h visible
        }
    }
    __syncthreads();

    // ---- Phase 4: attention (tanh proj -> softmax over t -> weighted sum) ----
    {
        const int t = tid;
        float hh[AD];
        #pragma unroll
        for (int i = 0; i < AD; ++i) hh[i] = h1_sh[t][i];
        float st = 0.0f;
        for (int i = 0; i < AD; ++i) {
            float acc = ba[i];
            #pragma unroll
            for (int k = 0; k < AD; ++k) acc += Wa[i * AD + k] * hh[k];
            st += fast_tanh(acc) * ctxv[i];
        }
        // softmax across the 128 threads (2 waves)
        float m = st;
        #pragma unroll
        for (int off = 32; off > 0; off >>= 1) m = fmaxf(m, __shfl_xor(m, off));
        if (lane == 0) red[wave] = m;
        __syncthreads();
        m = fmaxf(red[0], red[1]);
        const float e = __expf(st - m);
        float ssum = e;
        #pragma unroll
        for (int off = 32; off > 0; off >>= 1) ssum += __shfl_xor(ssum, off);
        if (lane == 0) red[2 + wave] = ssum;
        __syncthreads();
        const float Z = red[2] + red[3];
        w_sh[t] = e / Z;
    }
    __syncthreads();

    // cv[i] = sum_t w[t] * h1[t][i]
    if (tid < AD) {
        float acc = 0.0f;
        for (int t2 = 0; t2 < TSTEPS; ++t2)
            acc += w_sh[t2] * h1_sh[t2][tid];
        cv_sh[tid] = acc;
    }
    __syncthreads();

    if (HAS_PROJ) {
        if (tid < 16) {
            float acc = bm[tid];
            #pragma unroll
            for (int i = 0; i < AD; ++i) acc += Wm[tid * AD + i] * cv_sh[i];
            out[(size_t)seq * out_cols + tid] = acc;
        }
    } else {
        if (tid < AD) out[(size_t)seq * out_cols + tid] = cv_sh[tid];
    }
}

extern "C" void kernel_launch(void* const* d_in, const int* in_sizes, int n_in,
                              void* d_out, int out_size, void* d_ws, size_t ws_size,
                              hipStream_t stream) {
    const float* x     = (const float*)d_in[0];
    const float* Wih1f = (const float*)d_in[1];
    const float* Whh1f = (const float*)d_in[2];
    const float* bih1f = (const float*)d_in[3];
    const float* bhh1f = (const float*)d_in[4];
    const float* Wih1b = (const float*)d_in[5];
    const float* Whh1b = (const float*)d_in[6];
    const float* bih1b = (const float*)d_in[7];
    const float* bhh1b = (const float*)d_in[8];
    const float* Wih2f = (const float*)d_in[9];
    const float* Whh2f = (const float*)d_in[10];
    const float* bih2f = (const float*)d_in[11];
    const float* bhh2f = (const float*)d_in[12];
    const float* Wih2b = (const float*)d_in[13];
    const float* Whh2b = (const float*)d_in[14];
    const float* bih2b = (const float*)d_in[15];
    const float* bhh2b = (const float*)d_in[16];
    const float* Wa1   = (const float*)d_in[17];
    const float* ba1   = (const float*)d_in[18];
    const float* ctx1  = (const float*)d_in[19];
    const float* Wa2   = (const float*)d_in[20];
    const float* ba2   = (const float*)d_in[21];
    const float* ctx2  = (const float*)d_in[22];
    const float* Wm    = (const float*)d_in[23];
    const float* bm    = (const float*)d_in[24];

    float* flow = (float*)d_ws;          // [8192, 16]
    float* outp = (float*)d_out;         // [64, 32]

    // Stage 1: 8192 sequences (B*N), D=25 -> flow[8192][16]
    gru_attn_kernel<25, true><<<8192, 128, 0, stream>>>(
        x, Wih1f, Whh1f, bih1f, bhh1f, Wih1b, Whh1b, bih1b, bhh1b,
        Wa1, ba1, ctx1, Wm, bm, flow, 16);

    // Stage 2: 64 sequences (B), input = flow viewed as [64, 128, 16]
    gru_attn_kernel<16, false><<<64, 128, 0, stream>>>(
        flow, Wih2f, Whh2f, bih2f, bhh2f, Wih2b, Whh2b, bih2b, bhh2b,
        Wa2, ba2, ctx2, nullptr, nullptr, outp, 32);
}

// Round 2
// 586.097 us; speedup vs baseline: 1.9337x; 1.9337x over previous
//
#include <hip/hip_runtime.h>
#include <hip/hip_bf16.h>
#include <math.h>

#define TSTEPS 128
#define HD 16      // GRU hidden
#define G3 48      // 3*H gates
#define AD 32      // 2*H attention dim

typedef float v2f __attribute__((ext_vector_type(2)));

__device__ __forceinline__ float fast_sigmoid(float x) {
    return 1.0f / (1.0f + __expf(-x));
}
__device__ __forceinline__ float fast_tanh(float x) {
    // tanh(x) = 1 - 2/(exp(2x)+1); stable at both extremes
    return 1.0f - 2.0f / (__expf(2.0f * x) + 1.0f);
}

// One block = one sequence. 128 threads = 2 waves (wave0 fwd, wave1 bwd).
// Recurrence is barrier-free: each dir's hidden state stays within one wave.
template<int D, int PD, bool HAS_PROJ>
__global__ __launch_bounds__(128, 3)
void gru_attn_kernel(
    const float* __restrict__ x,                      // [S, TSTEPS, D]
    const float* __restrict__ Wih_f, const float* __restrict__ Whh_f,
    const float* __restrict__ bih_f, const float* __restrict__ bhh_f,
    const float* __restrict__ Wih_b, const float* __restrict__ Whh_b,
    const float* __restrict__ bih_b, const float* __restrict__ bhh_b,
    const float* __restrict__ Wa, const float* __restrict__ ba,
    const float* __restrict__ ctxv,
    const float* __restrict__ Wm, const float* __restrict__ bm,
    float* __restrict__ out, int out_cols)
{
    __shared__ __align__(16) float x_sh[TSTEPS * PD];   // padded rows, 16B-aligned
    __shared__ float h1_sh[TSTEPS][AD + 1];             // +1 pad: conflict-free cols
    __shared__ __align__(16) float h_b[2][HD];          // per-dir running hidden
    __shared__ float red[4];
    __shared__ float w_sh[TSTEPS];
    __shared__ float cv_sh[AD];

    const int tid  = threadIdx.x;
    const int seq  = blockIdx.x;
    const int lane = tid & 63;
    const int wave = tid >> 6;

    // ---- Phase 1: stage x into LDS (coalesced, padded rows, zero pad cols) ----
    const float* xp = x + (size_t)seq * TSTEPS * D;
    #pragma unroll 4
    for (int i = tid; i < TSTEPS * PD; i += 128) {
        const int t = i / PD;
        const int d = i - t * PD;
        x_sh[i] = (d < D) ? xp[t * D + d] : 0.0f;
    }
    if (tid < 2 * HD) h_b[tid >> 4][tid & 15] = 0.0f;
    __syncthreads();

    // ---- Phase 2: barrier-free sequential recurrence. wave0 = fwd, wave1 = bwd
    {
        const int dir = wave;
        const float* Wih = dir ? Wih_b : Wih_f;
        const float* Whh = dir ? Whh_b : Whh_f;
        const float* bihp = dir ? bih_b : bih_f;
        const float* bhhp = dir ? bhh_b : bhh_f;
        const int j = lane;              // gate index, valid for lane < 48

        v2f wih2[PD / 2];
        v2f whh2[HD / 2];
        float gb = 0.0f, bh = 0.0f;
        #pragma unroll
        for (int p = 0; p < PD / 2; ++p) wih2[p] = (v2f){0.0f, 0.0f};
        #pragma unroll
        for (int p = 0; p < HD / 2; ++p) whh2[p] = (v2f){0.0f, 0.0f};
        if (j < G3) {
            #pragma unroll
            for (int d = 0; d < D; ++d) wih2[d / 2][d & 1] = Wih[j * D + d];
            #pragma unroll
            for (int k = 0; k < HD; ++k) whh2[k / 2][k & 1] = Whh[j * HD + k];
            gb = bihp[j];
            bh = bhhp[j];
        }

        float h_own = 0.0f;              // lane k<16 keeps h[k]

        for (int s = 0; s < TSTEPS; ++s) {
            const int t = dir ? (TSTEPS - 1 - s) : s;

            // gx = bih + Wih[j,:] . x[t,:]   (broadcast x from LDS, packed fma)
            const float4* xr4 = reinterpret_cast<const float4*>(&x_sh[t * PD]);
            v2f ga0 = {gb, 0.0f}, ga1 = {0.0f, 0.0f};
            #pragma unroll
            for (int p = 0; p < PD / 4; ++p) {
                const float4 xv = xr4[p];
                const v2f xa = {xv.x, xv.y};
                const v2f xb = {xv.z, xv.w};
                ga0 += wih2[2 * p] * xa;
                ga1 += wih2[2 * p + 1] * xb;
            }
            const float gxv = ga0.x + ga0.y + ga1.x + ga1.y;

            // gh = bhh + Whh[j,:] . h      (broadcast h from per-dir LDS)
            const v2f* hb2 = reinterpret_cast<const v2f*>(&h_b[dir][0]);
            v2f ha0 = {bh, 0.0f}, ha1 = {0.0f, 0.0f};
            #pragma unroll
            for (int p = 0; p < HD / 4; ++p) {
                ha0 += whh2[2 * p] * hb2[2 * p];
                ha1 += whh2[2 * p + 1] * hb2[2 * p + 1];
            }
            const float ghv = ha0.x + ha0.y + ha1.x + ha1.y;

            // lanes 0..15: r | 16..31: z | 32..47: n
            const float sact = fast_sigmoid(gxv + ghv);
            const float r    = __shfl_xor(sact, 32);      // n-lanes fetch r
            const float nv   = fast_tanh(gxv + r * ghv);  // ghv includes bhh_n
            const float z    = __shfl_xor(sact, 16);      // h-lanes fetch z
            const float nn   = __shfl_xor(nv, 32);        // h-lanes fetch n
            const float h_new = (1.0f - z) * nn + z * h_own;

            if (lane < HD) {
                h_own = h_new;
                h_b[dir][lane] = h_new;                   // within-wave only
                h1_sh[t][dir * HD + lane] = h_new;
            }
        }
    }
    __syncthreads();

    // ---- Phase 3: attention (tanh proj -> softmax over t -> weighted sum) ----
    {
        const int t = tid;
        float hh[AD];
        #pragma unroll
        for (int i = 0; i < AD; ++i) hh[i] = h1_sh[t][i];
        float st = 0.0f;
        for (int i = 0; i < AD; ++i) {
            v2f acc = {ba[i], 0.0f};
            const v2f* wa2 = reinterpret_cast<const v2f*>(&Wa[i * AD]);
            #pragma unroll
            for (int k = 0; k < AD / 2; ++k) {
                const v2f hv = {hh[2 * k], hh[2 * k + 1]};
                acc += wa2[k] * hv;
            }
            st += fast_tanh(acc.x + acc.y) * ctxv[i];
        }
        // softmax across the 128 threads (2 waves)
        float m = st;
        #pragma unroll
        for (int off = 32; off > 0; off >>= 1) m = fmaxf(m, __shfl_xor(m, off));
        if (lane == 0) red[wave] = m;
        __syncthreads();
        m = fmaxf(red[0], red[1]);
        const float e = __expf(st - m);
        float ssum = e;
        #pragma unroll
        for (int off = 32; off > 0; off >>= 1) ssum += __shfl_xor(ssum, off);
        if (lane == 0) red[2 + wave] = ssum;
        __syncthreads();
        const float Z = red[2] + red[3];
        w_sh[t] = e / Z;
    }
    __syncthreads();

    // cv[i] = sum_t w[t] * h1[t][i]
    if (tid < AD) {
        float acc = 0.0f;
        for (int t2 = 0; t2 < TSTEPS; ++t2)
            acc += w_sh[t2] * h1_sh[t2][tid];
        cv_sh[tid] = acc;
    }
    __syncthreads();

    if (HAS_PROJ) {
        if (tid < 16) {
            float acc = bm[tid];
            #pragma unroll
            for (int i = 0; i < AD; ++i) acc += Wm[tid * AD + i] * cv_sh[i];
            out[(size_t)seq * out_cols + tid] = acc;
        }
    } else {
        if (tid < AD) out[(size_t)seq * out_cols + tid] = cv_sh[tid];
    }
}

extern "C" void kernel_launch(void* const* d_in, const int* in_sizes, int n_in,
                              void* d_out, int out_size, void* d_ws, size_t ws_size,
                              hipStream_t stream) {
    const float* x     = (const float*)d_in[0];
    const float* Wih1f = (const float*)d_in[1];
    const float* Whh1f = (const float*)d_in[2];
    const float* bih1f = (const float*)d_in[3];
    const float* bhh1f = (const float*)d_in[4];
    const float* Wih1b = (const float*)d_in[5];
    const float* Whh1b = (const float*)d_in[6];
    const float* bih1b = (const float*)d_in[7];
    const float* bhh1b = (const float*)d_in[8];
    const float* Wih2f = (const float*)d_in[9];
    const float* Whh2f = (const float*)d_in[10];
    const float* bih2f = (const float*)d_in[11];
    const float* bhh2f = (const float*)d_in[12];
    const float* Wih2b = (const float*)d_in[13];
    const float* Whh2b = (const float*)d_in[14];
    const float* bih2b = (const float*)d_in[15];
    const float* bhh2b = (const float*)d_in[16];
    const float* Wa1   = (const float*)d_in[17];
    const float* ba1   = (const float*)d_in[18];
    const float* ctx1  = (const float*)d_in[19];
    const float* Wa2   = (const float*)d_in[20];
    const float* ba2   = (const float*)d_in[21];
    const float* ctx2  = (const float*)d_in[22];
    const float* Wm    = (const float*)d_in[23];
    const float* bm    = (const float*)d_in[24];

    float* flow = (float*)d_ws;          // [8192, 16]
    float* outp = (float*)d_out;         // [64, 32]

    // Stage 1: 8192 sequences (B*N), D=25 (rows padded to 28) -> flow[8192][16]
    gru_attn_kernel<25, 28, true><<<8192, 128, 0, stream>>>(
        x, Wih1f, Whh1f, bih1f, bhh1f, Wih1b, Whh1b, bih1b, bhh1b,
        Wa1, ba1, ctx1, Wm, bm, flow, 16);

    // Stage 2: 64 sequences (B), input = flow viewed as [64, 128, 16]
    gru_attn_kernel<16, 16, false><<<64, 128, 0, stream>>>(
        flow, Wih2f, Whh2f, bih2f, bhh2f, Wih2b, Whh2b, bih2b, bhh2b,
        Wa2, ba2, ctx2, nullptr, nullptr, outp, 32);
}

// Round 3
// 423.658 us; speedup vs baseline: 2.6751x; 1.3834x over previous
//
#include <hip/hip_runtime.h>
#include <hip/hip_bf16.h>
#include <math.h>

#define TSTEPS 128
#define HD 16      // GRU hidden
#define G3 48      // 3*H gates
#define AD 32      // 2*H attention dim
#define H1P 36     // padded h1 row (halfs): 72B rows, 8B-aligned

typedef _Float16 h2 __attribute__((ext_vector_type(2)));
typedef _Float16 h4 __attribute__((ext_vector_type(4)));
typedef float v2f __attribute__((ext_vector_type(2)));

__device__ __forceinline__ float fast_sigmoid(float x) {
    return 1.0f / (1.0f + __expf(-x));
}
__device__ __forceinline__ float fast_tanh(float x) {
    return 1.0f - 2.0f / (__expf(2.0f * x) + 1.0f);
}
__device__ __forceinline__ float fdot2(h2 a, h2 b, float c) {
    return __builtin_amdgcn_fdot2(a, b, c, false);
}

// One block = one sequence. 128 threads = 2 waves (wave0 fwd, wave1 bwd).
// Recurrence is barrier-free: each dir's hidden state stays within its wave.
template<int D, int PDH, bool HAS_PROJ>
__global__ __launch_bounds__(128, 4)
void gru_attn_kernel(
    const float* __restrict__ x,                      // [S, TSTEPS, D]
    const float* __restrict__ Wih_f, const float* __restrict__ Whh_f,
    const float* __restrict__ bih_f, const float* __restrict__ bhh_f,
    const float* __restrict__ Wih_b, const float* __restrict__ Whh_b,
    const float* __restrict__ bih_b, const float* __restrict__ bhh_b,
    const float* __restrict__ Wa, const float* __restrict__ ba,
    const float* __restrict__ ctxv,
    const float* __restrict__ Wm, const float* __restrict__ bm,
    float* __restrict__ out, int out_cols)
{
    __shared__ __align__(16) _Float16 x_sh[TSTEPS * PDH];   // fp16 padded rows
    __shared__ __align__(16) _Float16 h1_sh[TSTEPS][H1P];   // fp16 hidden history
    __shared__ float red[4];
    __shared__ float w_sh[TSTEPS];
    __shared__ float cvp[4][AD];

    const int tid  = threadIdx.x;
    const int seq  = blockIdx.x;
    const int lane = tid & 63;
    const int wave = tid >> 6;

    // ---- Phase 1: stage x into LDS as fp16 (zero-filled pad cols) ----
    const float* xp = x + (size_t)seq * TSTEPS * D;
    for (int i = tid; i < TSTEPS * PDH; i += 128) {
        const int t = i / PDH;
        const int d = i - t * PDH;
        x_sh[i] = (d < D) ? (_Float16)xp[t * D + d] : (_Float16)0.0f;
    }
    __syncthreads();

    // ---- Phase 2: barrier-free sequential recurrence. wave0 = fwd, wave1 = bwd
    {
        const int dir = wave;
        const float* Wih = dir ? Wih_b : Wih_f;
        const float* Whh = dir ? Whh_b : Whh_f;
        const float* bihp = dir ? bih_b : bih_f;
        const float* bhhp = dir ? bhh_b : bhh_f;
        const int j = lane;              // gate index, valid for lane < 48

        h2 wih[PDH / 2];
        h2 whh[HD / 2];
        float gb = 0.0f, bh = 0.0f;
        #pragma unroll
        for (int p = 0; p < PDH / 2; ++p) wih[p] = (h2){(_Float16)0.0f, (_Float16)0.0f};
        #pragma unroll
        for (int p = 0; p < HD / 2; ++p) whh[p] = (h2){(_Float16)0.0f, (_Float16)0.0f};
        if (j < G3) {
            #pragma unroll
            for (int d = 0; d < D; ++d) wih[d / 2][d & 1] = (_Float16)Wih[j * D + d];
            #pragma unroll
            for (int k = 0; k < HD; ++k) whh[k / 2][k & 1] = (_Float16)Whh[j * HD + k];
            gb = bihp[j];
            bh = bhhp[j];
        }

        float h_own = 0.0f;              // lane k<16 keeps h[k]

        #pragma unroll 2
        for (int s = 0; s < TSTEPS; ++s) {
            const int t = dir ? (TSTEPS - 1 - s) : s;

            // gx = bih + Wih[j,:] . x[t,:]  (broadcast fp16 LDS, dot2 f32-accum)
            const h4* xr = reinterpret_cast<const h4*>(&x_sh[t * PDH]);
            float a0 = gb, a1 = 0.0f, a2 = 0.0f, a3 = 0.0f;
            #pragma unroll
            for (int p = 0; p < PDH / 4; ++p) {
                const h4 xv = xr[p];
                const h2 lo = {xv.x, xv.y};
                const h2 hi = {xv.z, xv.w};
                if (p & 1) {
                    a2 = fdot2(wih[2 * p], lo, a2);
                    a3 = fdot2(wih[2 * p + 1], hi, a3);
                } else {
                    a0 = fdot2(wih[2 * p], lo, a0);
                    a1 = fdot2(wih[2 * p + 1], hi, a1);
                }
            }
            const float gxv = (a0 + a2) + (a1 + a3);

            // gh = bhh + Whh[j,:] . h[t_prev]  (read prev h from h1_sh)
            float ghv;
            if (s == 0) {
                ghv = bh;
            } else {
                const int tp = dir ? (t + 1) : (t - 1);
                const h4* hr = reinterpret_cast<const h4*>(&h1_sh[tp][dir * HD]);
                float b0 = bh, b1 = 0.0f;
                #pragma unroll
                for (int p = 0; p < HD / 4; ++p) {
                    const h4 hv = hr[p];
                    const h2 lo = {hv.x, hv.y};
                    const h2 hi = {hv.z, hv.w};
                    b0 = fdot2(whh[2 * p], lo, b0);
                    b1 = fdot2(whh[2 * p + 1], hi, b1);
                }
                ghv = b0 + b1;
            }

            // lanes 0..15: r | 16..31: z | 32..47: n
            const float sact = fast_sigmoid(gxv + ghv);
            const float r    = __shfl_xor(sact, 32);      // n-lanes fetch r
            const float nv   = fast_tanh(gxv + r * ghv);  // ghv includes bhh_n
            const float z    = __shfl_xor(sact, 16);      // h-lanes fetch z
            const float nn   = __shfl_xor(nv, 32);        // h-lanes fetch n
            const float h_new = (1.0f - z) * nn + z * h_own;

            if (lane < HD) {
                h_own = h_new;
                h1_sh[t][dir * HD + lane] = (_Float16)h_new;  // within-wave only
            }
        }
    }
    __syncthreads();

    // ---- Phase 3: attention (tanh proj -> softmax over t -> weighted sum) ----
    {
        const int t = tid;
        float hh[AD];
        const h4* hr = reinterpret_cast<const h4*>(&h1_sh[t][0]);
        #pragma unroll
        for (int p = 0; p < AD / 4; ++p) {
            const h4 v = hr[p];
            hh[4 * p + 0] = (float)v.x;
            hh[4 * p + 1] = (float)v.y;
            hh[4 * p + 2] = (float)v.z;
            hh[4 * p + 3] = (float)v.w;
        }
        float st = 0.0f;
        for (int i = 0; i < AD; ++i) {
            v2f acc = {ba[i], 0.0f};
            const v2f* wa2 = reinterpret_cast<const v2f*>(&Wa[i * AD]);
            #pragma unroll
            for (int k = 0; k < AD / 2; ++k) {
                const v2f hv = {hh[2 * k], hh[2 * k + 1]};
                acc += wa2[k] * hv;
            }
            st += fast_tanh(acc.x + acc.y) * ctxv[i];
        }
        // softmax across the 128 threads (2 waves)
        float m = st;
        #pragma unroll
        for (int off = 32; off > 0; off >>= 1) m = fmaxf(m, __shfl_xor(m, off));
        if (lane == 0) red[wave] = m;
        __syncthreads();
        m = fmaxf(red[0], red[1]);
        const float e = __expf(st - m);
        float ssum = e;
        #pragma unroll
        for (int off = 32; off > 0; off >>= 1) ssum += __shfl_xor(ssum, off);
        if (lane == 0) red[2 + wave] = ssum;
        __syncthreads();
        const float Z = red[2] + red[3];
        w_sh[t] = e / Z;
    }
    __syncthreads();

    // cv[i] = sum_t w[t] * h1[t][i]   (4 partial groups of 32 t's each)
    {
        const int g = tid >> 5, i = tid & 31;
        float acc = 0.0f;
        for (int tt = g * 32; tt < g * 32 + 32; ++tt)
            acc += w_sh[tt] * (float)h1_sh[tt][i];
        cvp[g][i] = acc;
    }
    __syncthreads();
    if (tid < AD) cvp[0][tid] = cvp[0][tid] + cvp[1][tid] + cvp[2][tid] + cvp[3][tid];
    __syncthreads();

    if (HAS_PROJ) {
        if (tid < 16) {
            float acc = bm[tid];
            #pragma unroll
            for (int i = 0; i < AD; ++i) acc += Wm[tid * AD + i] * cvp[0][i];
            out[(size_t)seq * out_cols + tid] = acc;
        }
    } else {
        if (tid < AD) out[(size_t)seq * out_cols + tid] = cvp[0][tid];
    }
}

extern "C" void kernel_launch(void* const* d_in, const int* in_sizes, int n_in,
                              void* d_out, int out_size, void* d_ws, size_t ws_size,
                              hipStream_t stream) {
    const float* x     = (const float*)d_in[0];
    const float* Wih1f = (const float*)d_in[1];
    const float* Whh1f = (const float*)d_in[2];
    const float* bih1f = (const float*)d_in[3];
    const float* bhh1f = (const float*)d_in[4];
    const float* Wih1b = (const float*)d_in[5];
    const float* Whh1b = (const float*)d_in[6];
    const float* bih1b = (const float*)d_in[7];
    const float* bhh1b = (const float*)d_in[8];
    const float* Wih2f = (const float*)d_in[9];
    const float* Whh2f = (const float*)d_in[10];
    const float* bih2f = (const float*)d_in[11];
    const float* bhh2f = (const float*)d_in[12];
    const float* Wih2b = (const float*)d_in[13];
    const float* Whh2b = (const float*)d_in[14];
    const float* bih2b = (const float*)d_in[15];
    const float* bhh2b = (const float*)d_in[16];
    const float* Wa1   = (const float*)d_in[17];
    const float* ba1   = (const float*)d_in[18];
    const float* ctx1  = (const float*)d_in[19];
    const float* Wa2   = (const float*)d_in[20];
    const float* ba2   = (const float*)d_in[21];
    const float* ctx2  = (const float*)d_in[22];
    const float* Wm    = (const float*)d_in[23];
    const float* bm    = (const float*)d_in[24];

    float* flow = (float*)d_ws;          // [8192, 16]
    float* outp = (float*)d_out;         // [64, 32]

    // Stage 1: 8192 sequences (B*N), D=25 (rows padded to 28 halfs)
    gru_attn_kernel<25, 28, true><<<8192, 128, 0, stream>>>(
        x, Wih1f, Whh1f, bih1f, bhh1f, Wih1b, Whh1b, bih1b, bhh1b,
        Wa1, ba1, ctx1, Wm, bm, flow, 16);

    // Stage 2: 64 sequences (B), input = flow viewed as [64, 128, 16]
    gru_attn_kernel<16, 16, false><<<64, 128, 0, stream>>>(
        flow, Wih2f, Whh2f, bih2f, bhh2f, Wih2b, Whh2b, bih2b, bhh2b,
        Wa2, ba2, ctx2, nullptr, nullptr, outp, 32);
}